// Round 1
// baseline (215.994 us; speedup 1.0000x reference)
//
#include <hip/hip_runtime.h>
#include <stdint.h>

// Problem constants (from reference setup_inputs)
#define BB 4
#define SS 512
#define EE 64
#define VV 50257
#define KK 250        // K_VAL
// STEP_SIZE = 0.1 -> multiply by 10; TEMP = 1.0 -> no-op

#define CAP 4096
#define NTHREADS 256

__device__ __forceinline__ unsigned fkey(float f) {
    // monotonic map: larger float -> larger unsigned
    unsigned u = __float_as_uint(f);
    return (u & 0x80000000u) ? ~u : (u | 0x80000000u);
}

__global__ __launch_bounds__(NTHREADS, 4)
void langevin_topk_kernel(const float* __restrict__ gx,
                          const float* __restrict__ cb,
                          const float* __restrict__ W,
                          const float* __restrict__ logits,
                          float* __restrict__ out0,   // filtered [B*S, K]
                          float* __restrict__ out1)   // ids as float [B*S, K]
{
    // LDS: candidate array (32 KB); histogram (16 KB) + chunk sums (1 KB)
    // alias onto it (hist/chunkSum are dead before cand is first written).
    __shared__ unsigned long long cand[CAP];
    unsigned* hist = (unsigned*)cand;                 // [4096]
    unsigned* chunkSum = ((unsigned*)cand) + 4096;    // [256]
    __shared__ float gx_s[EE], cb_s[EE];
    __shared__ unsigned sThreshKey;
    __shared__ unsigned sCnt;

    const int row = blockIdx.x;          // b*S + s
    const int tid = threadIdx.x;
    const float* rp = logits + (size_t)row * VV;

    for (int i = tid; i < 4096; i += NTHREADS) hist[i] = 0u;
    if (tid < EE) {
        gx_s[tid] = gx[(size_t)row * EE + tid];
        cb_s[tid] = cb[(size_t)row * EE + tid];
    }
    if (tid == 0) sCnt = 0u;
    __syncthreads();

    // ---- alignment peel: row offset = row*50257 elements, 50257 % 4 == 1 ----
    const int mis  = row & 3;                 // element offset mod 4
    const int peel = (4 - mis) & 3;           // elements until 16B alignment
    const int nb   = (VV - peel) >> 2;        // float4 body count
    const int tail0 = peel + nb * 4;
    const float4* rp4 = (const float4*)(rp + peel);

    // ---- pass 1: histogram of top-12 key bits ----
    if (tid < peel) atomicAdd(&hist[fkey(rp[tid]) >> 20], 1u);
    for (int i = tid; i < nb; i += NTHREADS) {
        float4 v = rp4[i];
        atomicAdd(&hist[fkey(v.x) >> 20], 1u);
        atomicAdd(&hist[fkey(v.y) >> 20], 1u);
        atomicAdd(&hist[fkey(v.z) >> 20], 1u);
        atomicAdd(&hist[fkey(v.w) >> 20], 1u);
    }
    for (int i = tail0 + tid; i < VV; i += NTHREADS) {
        atomicAdd(&hist[fkey(rp[i]) >> 20], 1u);
    }
    __syncthreads();

    // ---- find threshold bin: suffix sums over 256 chunks of 16 bins ----
    unsigned cs = 0;
    #pragma unroll
    for (int b = 0; b < 16; ++b) cs += hist[tid * 16 + b];
    chunkSum[tid] = cs;
    __syncthreads();

    unsigned g = 0;  // count of elements in chunks strictly above mine
    for (int u = tid + 1; u < NTHREADS; ++u) g += chunkSum[u];
    if (g < KK && g + cs >= KK) {
        unsigned cum = g;
        #pragma unroll
        for (int b = 15; b >= 0; --b) {
            unsigned c = hist[tid * 16 + b];
            if (cum + c >= KK) { sThreshKey = ((unsigned)(tid * 16 + b)) << 20; break; }
            cum += c;
        }
    }
    __syncthreads();
    const unsigned keyT = sThreshKey;
    __syncthreads();   // everyone has keyT; hist/chunkSum now dead -> cand may be written

    // ---- pass 2: collect candidates (bin >= threshold bin) ----
    if (tid < peel) {
        unsigned k = fkey(rp[tid]);
        if (k >= keyT) {
            unsigned p = atomicAdd(&sCnt, 1u);
            if (p < CAP) cand[p] = ((unsigned long long)k << 32) | (unsigned)(~tid);
        }
    }
    for (int i = tid; i < nb; i += NTHREADS) {
        float4 v = rp4[i];
        int base = peel + i * 4;
        unsigned k0 = fkey(v.x), k1 = fkey(v.y), k2 = fkey(v.z), k3 = fkey(v.w);
        if (k0 >= keyT) { unsigned p = atomicAdd(&sCnt, 1u); if (p < CAP) cand[p] = ((unsigned long long)k0 << 32) | (unsigned)(~(base + 0)); }
        if (k1 >= keyT) { unsigned p = atomicAdd(&sCnt, 1u); if (p < CAP) cand[p] = ((unsigned long long)k1 << 32) | (unsigned)(~(base + 1)); }
        if (k2 >= keyT) { unsigned p = atomicAdd(&sCnt, 1u); if (p < CAP) cand[p] = ((unsigned long long)k2 << 32) | (unsigned)(~(base + 2)); }
        if (k3 >= keyT) { unsigned p = atomicAdd(&sCnt, 1u); if (p < CAP) cand[p] = ((unsigned long long)k3 << 32) | (unsigned)(~(base + 3)); }
    }
    for (int i = tail0 + tid; i < VV; i += NTHREADS) {
        unsigned k = fkey(rp[i]);
        if (k >= keyT) {
            unsigned p = atomicAdd(&sCnt, 1u);
            if (p < CAP) cand[p] = ((unsigned long long)k << 32) | (unsigned)(~i);
        }
    }
    __syncthreads();

    unsigned ncand = sCnt;
    if (ncand > CAP) ncand = CAP;
    unsigned P = 256;
    while (P < ncand) P <<= 1;
    for (unsigned i = ncand + tid; i < P; i += NTHREADS) cand[i] = 0ull;
    __syncthreads();

    // ---- bitonic sort descending on composite key ----
    for (unsigned k = 2; k <= P; k <<= 1) {
        for (unsigned j = k >> 1; j > 0; j >>= 1) {
            for (unsigned i = tid; i < P; i += NTHREADS) {
                unsigned l = i ^ j;
                if (l > i) {
                    unsigned long long a = cand[i], b = cand[l];
                    bool up = ((i & k) == 0);
                    if (up ? (a < b) : (a > b)) { cand[i] = b; cand[l] = a; }
                }
            }
            __syncthreads();
        }
    }

    // ---- epilogue: proposal value at the K selected ids ----
    float gxcb = 0.f, cbn = 0.f;
    #pragma unroll
    for (int e = 0; e < EE; ++e) { gxcb += gx_s[e] * cb_s[e]; cbn += cb_s[e] * cb_s[e]; }

    if (tid < KK) {
        unsigned long long ck = cand[tid];
        unsigned v = ~((unsigned)ck);
        const float4* Wv = (const float4*)(W + (size_t)v * EE);
        float d1 = 0.f, d2 = 0.f, wn = 0.f;
        #pragma unroll
        for (int j2 = 0; j2 < 16; ++j2) {
            float4 w = Wv[j2];
            float a0 = gx_s[4*j2+0], a1 = gx_s[4*j2+1], a2 = gx_s[4*j2+2], a3 = gx_s[4*j2+3];
            float b0 = cb_s[4*j2+0], b1 = cb_s[4*j2+1], b2 = cb_s[4*j2+2], b3 = cb_s[4*j2+3];
            d1 += a0*w.x + a1*w.y + a2*w.z + a3*w.w;
            d2 += b0*w.x + b1*w.y + b2*w.z + b3*w.w;
            wn += w.x*w.x + w.y*w.y + w.z*w.z + w.w*w.w;
        }
        // dist = 0.5*(t1_1 - t1_2) + (t2_1 - 2*t2_2 + t2_3)/0.1 ; out = -dist / TEMP
        float unf = -(0.5f * (d1 - gxcb) + (wn - 2.0f * d2 + cbn) * 10.0f);
        out0[(size_t)row * KK + tid] = unf;
        out1[(size_t)row * KK + tid] = (float)v;
    }
}

extern "C" void kernel_launch(void* const* d_in, const int* in_sizes, int n_in,
                              void* d_out, int out_size, void* d_ws, size_t ws_size,
                              hipStream_t stream) {
    const float* gx = (const float*)d_in[0];      // [B,S,E]
    const float* cb = (const float*)d_in[1];      // [B,S,E]
    const float* W  = (const float*)d_in[2];      // [V,E]
    const float* lg = (const float*)d_in[3];      // [B,S,V]
    float* out0 = (float*)d_out;                       // filtered, 512000 floats
    float* out1 = out0 + (size_t)BB * SS * KK;         // ids as float, 512000

    dim3 grid(BB * SS), block(NTHREADS);
    hipLaunchKernelGGL(langevin_topk_kernel, grid, block, 0, stream,
                       gx, cb, W, lg, out0, out1);
}

// Round 2
// 169.048 us; speedup vs baseline: 1.2777x; 1.2777x over previous
//
#include <hip/hip_runtime.h>
#include <stdint.h>

// Problem constants (from reference setup_inputs)
#define BB 4
#define SS 512
#define EE 64
#define VV 50257
#define KK 250        // K_VAL
// STEP_SIZE = 0.1 -> multiply by 10; TEMP = 1.0 -> no-op

#define CAP 4096
#define NT 512

// fkey(2.0f) = 0xC0000000 : static pre-filter threshold for the fast path.
// Correctness does NOT depend on it: if fewer than KK values exceed it (or
// more than CAP do), the kernel falls back to an exact full-histogram path.
#define K0 0xC0000000u
#define BIN0 3072u    // K0 >> 20

__device__ __forceinline__ unsigned fkey(float f) {
    // monotonic map: larger float -> larger unsigned
    unsigned u = __float_as_uint(f);
    return (u & 0x80000000u) ? ~u : (u | 0x80000000u);
}

__global__ __launch_bounds__(NT, 8)
void langevin_topk_kernel(const float* __restrict__ gx,
                          const float* __restrict__ cb,
                          const float* __restrict__ W,
                          const float* __restrict__ logits,
                          float* __restrict__ out0,   // filtered [B*S, K]
                          float* __restrict__ out1)   // ids as float [B*S, K]
{
    __shared__ unsigned long long cand[CAP];   // 32 KB candidate buffer
    __shared__ unsigned long long buf2[512];   // 4 KB compact buffer; fast-path hist aliases
    __shared__ unsigned chunkSum[256];         // 1 KB
    __shared__ float gx_s[EE], cb_s[EE];
    __shared__ unsigned sThreshKey, sCnt, sCnt2;

    const int row  = blockIdx.x;               // b*S + s
    const int tid  = threadIdx.x;
    const int lane = tid & 63;
    const float* rp = logits + (size_t)row * VV;

    unsigned* hist = (unsigned*)buf2;          // 1024 bins, fast path only

    for (int i = tid; i < 1024; i += NT) hist[i] = 0u;
    if (tid < EE) {
        gx_s[tid] = gx[(size_t)row * EE + tid];
        cb_s[tid] = cb[(size_t)row * EE + tid];
    }
    if (tid == 0) { sCnt = 0u; sCnt2 = 0u; }
    __syncthreads();

    // wave-aggregated candidate emit (1 LDS atomic per wave per step)
    auto emit = [&](unsigned k, int idx) {
        bool pred = (k >= K0);
        unsigned long long m = __ballot(pred ? 1 : 0);
        if (m != 0ull) {
            int leader = __ffsll(m) - 1;
            unsigned base = 0;
            if (lane == leader) base = atomicAdd(&sCnt, (unsigned)__popcll(m));
            base = __shfl(base, leader);
            if (pred) {
                unsigned p = base + (unsigned)__popcll(m & ((1ull << lane) - 1ull));
                if (p < CAP) cand[p] = ((unsigned long long)k << 32) | (unsigned)(~idx);
            }
        }
    };

    // ---- alignment peel: row offset = row*50257, 50257 % 4 == 1 ----
    const int mis  = row & 3;
    const int peel = (4 - mis) & 3;
    const int nb   = (VV - peel) >> 2;
    const int tail0 = peel + nb * 4;
    const float4* rp4 = (const float4*)(rp + peel);

    // ---- single streaming pass: collect candidates >= 2.0, 4 loads in flight ----
    if (tid < peel) emit(fkey(rp[tid]), tid);
    int i = tid;
    for (; i + 3 * NT < nb; i += 4 * NT) {
        float4 a = rp4[i], b = rp4[i + NT], c = rp4[i + 2 * NT], d = rp4[i + 3 * NT];
        int ia = peel + 4 * i, ib = peel + 4 * (i + NT), ic = peel + 4 * (i + 2 * NT), id_ = peel + 4 * (i + 3 * NT);
        emit(fkey(a.x), ia + 0); emit(fkey(a.y), ia + 1); emit(fkey(a.z), ia + 2); emit(fkey(a.w), ia + 3);
        emit(fkey(b.x), ib + 0); emit(fkey(b.y), ib + 1); emit(fkey(b.z), ib + 2); emit(fkey(b.w), ib + 3);
        emit(fkey(c.x), ic + 0); emit(fkey(c.y), ic + 1); emit(fkey(c.z), ic + 2); emit(fkey(c.w), ic + 3);
        emit(fkey(d.x), id_ + 0); emit(fkey(d.y), id_ + 1); emit(fkey(d.z), id_ + 2); emit(fkey(d.w), id_ + 3);
    }
    for (; i < nb; i += NT) {
        float4 a = rp4[i];
        int ia = peel + 4 * i;
        emit(fkey(a.x), ia + 0); emit(fkey(a.y), ia + 1); emit(fkey(a.z), ia + 2); emit(fkey(a.w), ia + 3);
    }
    for (int t = tail0 + tid; t < VV; t += NT) emit(fkey(rp[t]), t);
    __syncthreads();

    const unsigned n0 = sCnt;
    unsigned long long* srt;
    unsigned P;

    if (n0 >= KK && n0 <= CAP) {
        // ================= FAST PATH =================
        // histogram the collected candidates (bins >= BIN0 only)
        for (unsigned j = tid; j < n0; j += NT)
            atomicAdd(&hist[((unsigned)(cand[j] >> 32) >> 20) - BIN0], 1u);
        __syncthreads();

        if (tid < 256) {
            chunkSum[tid] = hist[tid * 4] + hist[tid * 4 + 1] + hist[tid * 4 + 2] + hist[tid * 4 + 3];
        }
        __syncthreads();
        if (tid < 256) {
            unsigned g = 0;
            for (int u = tid + 1; u < 256; ++u) g += chunkSum[u];
            unsigned cs = chunkSum[tid];
            if (g < KK && g + cs >= KK) {
                unsigned cum = g;
                #pragma unroll
                for (int b = 3; b >= 0; --b) {
                    unsigned c = hist[tid * 4 + b];
                    if (cum + c >= KK) { sThreshKey = ((unsigned)(tid * 4 + b) + BIN0) << 20; break; }
                    cum += c;
                }
            }
        }
        __syncthreads();
        const unsigned keyT = sThreshKey;
        __syncthreads();   // hist (aliases buf2) dead; buf2 may now be written

        // compact survivors (>= keyT) into buf2
        for (unsigned j = tid; j < n0; j += NT) {
            unsigned long long c = cand[j];
            if ((unsigned)(c >> 32) >= keyT) {
                unsigned p = atomicAdd(&sCnt2, 1u);
                if (p < 512) buf2[p] = c;
            }
        }
        __syncthreads();
        unsigned nc = sCnt2;
        if (nc <= 512) {
            srt = buf2;
            P = 256; while (P < nc) P <<= 1;
            for (unsigned j = nc + tid; j < P; j += NT) buf2[j] = 0ull;
        } else {
            // threshold bin unusually fat: sort the whole candidate buffer
            srt = cand;
            P = 256; while (P < n0) P <<= 1;
            for (unsigned j = n0 + tid; j < P; j += NT) cand[j] = 0ull;
        }
        __syncthreads();
    } else {
        // ================= EXACT FALLBACK (never taken for N(0,1) data) =================
        unsigned* hist4 = (unsigned*)cand;     // 4096 bins alias candidate space
        for (int j = tid; j < 4096; j += NT) hist4[j] = 0u;
        if (tid == 0) sCnt = 0u;
        __syncthreads();
        if (tid < peel) atomicAdd(&hist4[fkey(rp[tid]) >> 20], 1u);
        for (int j = tid; j < nb; j += NT) {
            float4 v = rp4[j];
            atomicAdd(&hist4[fkey(v.x) >> 20], 1u);
            atomicAdd(&hist4[fkey(v.y) >> 20], 1u);
            atomicAdd(&hist4[fkey(v.z) >> 20], 1u);
            atomicAdd(&hist4[fkey(v.w) >> 20], 1u);
        }
        for (int t = tail0 + tid; t < VV; t += NT) atomicAdd(&hist4[fkey(rp[t]) >> 20], 1u);
        __syncthreads();
        if (tid < 256) {
            unsigned cs = 0;
            #pragma unroll
            for (int b = 0; b < 16; ++b) cs += hist4[tid * 16 + b];
            chunkSum[tid] = cs;
        }
        __syncthreads();
        if (tid < 256) {
            unsigned g = 0;
            for (int u = tid + 1; u < 256; ++u) g += chunkSum[u];
            unsigned cs = chunkSum[tid];
            if (g < KK && g + cs >= KK) {
                unsigned cum = g;
                #pragma unroll
                for (int b = 15; b >= 0; --b) {
                    unsigned c = hist4[tid * 16 + b];
                    if (cum + c >= KK) { sThreshKey = ((unsigned)(tid * 16 + b)) << 20; break; }
                    cum += c;
                }
            }
        }
        __syncthreads();
        const unsigned keyT = sThreshKey;
        __syncthreads();   // hist4 aliases cand -> must drain before collection writes

        auto emit2 = [&](unsigned k, int idx) {
            if (k >= keyT) {
                unsigned p = atomicAdd(&sCnt, 1u);
                if (p < CAP) cand[p] = ((unsigned long long)k << 32) | (unsigned)(~idx);
            }
        };
        if (tid < peel) emit2(fkey(rp[tid]), tid);
        for (int j = tid; j < nb; j += NT) {
            float4 v = rp4[j];
            int ia = peel + 4 * j;
            emit2(fkey(v.x), ia + 0); emit2(fkey(v.y), ia + 1);
            emit2(fkey(v.z), ia + 2); emit2(fkey(v.w), ia + 3);
        }
        for (int t = tail0 + tid; t < VV; t += NT) emit2(fkey(rp[t]), t);
        __syncthreads();
        unsigned n1 = sCnt; if (n1 > CAP) n1 = CAP;
        srt = cand;
        P = 256; while (P < n1) P <<= 1;
        for (unsigned j = n1 + tid; j < P; j += NT) cand[j] = 0ull;
        __syncthreads();
    }

    // ---- bitonic sort descending on composite (key<<32 | ~idx) ----
    for (unsigned k = 2; k <= P; k <<= 1) {
        for (unsigned j = k >> 1; j > 0; j >>= 1) {
            for (unsigned i2 = tid; i2 < P; i2 += NT) {
                unsigned l = i2 ^ j;
                if (l > i2) {
                    unsigned long long a = srt[i2], b = srt[l];
                    bool up = ((i2 & k) == 0);
                    if (up ? (a < b) : (a > b)) { srt[i2] = b; srt[l] = a; }
                }
            }
            __syncthreads();
        }
    }

    // ---- epilogue: proposal value at the K selected ids ----
    float gxcb = 0.f, cbn = 0.f;
    #pragma unroll
    for (int e = 0; e < EE; ++e) { gxcb += gx_s[e] * cb_s[e]; cbn += cb_s[e] * cb_s[e]; }

    if (tid < KK) {
        unsigned long long ck = srt[tid];
        unsigned v = ~((unsigned)ck);
        const float4* Wv = (const float4*)(W + (size_t)v * EE);
        float d1 = 0.f, d2 = 0.f, wn = 0.f;
        #pragma unroll
        for (int j2 = 0; j2 < 16; ++j2) {
            float4 w = Wv[j2];
            float a0 = gx_s[4*j2+0], a1 = gx_s[4*j2+1], a2 = gx_s[4*j2+2], a3 = gx_s[4*j2+3];
            float b0 = cb_s[4*j2+0], b1 = cb_s[4*j2+1], b2 = cb_s[4*j2+2], b3 = cb_s[4*j2+3];
            d1 += a0*w.x + a1*w.y + a2*w.z + a3*w.w;
            d2 += b0*w.x + b1*w.y + b2*w.z + b3*w.w;
            wn += w.x*w.x + w.y*w.y + w.z*w.z + w.w*w.w;
        }
        // dist = 0.5*(t1_1 - t1_2) + (t2_1 - 2*t2_2 + t2_3)/0.1 ; out = -dist / TEMP
        float unf = -(0.5f * (d1 - gxcb) + (wn - 2.0f * d2 + cbn) * 10.0f);
        out0[(size_t)row * KK + tid] = unf;
        out1[(size_t)row * KK + tid] = (float)v;
    }
}

extern "C" void kernel_launch(void* const* d_in, const int* in_sizes, int n_in,
                              void* d_out, int out_size, void* d_ws, size_t ws_size,
                              hipStream_t stream) {
    const float* gx = (const float*)d_in[0];      // [B,S,E]
    const float* cb = (const float*)d_in[1];      // [B,S,E]
    const float* W  = (const float*)d_in[2];      // [V,E]
    const float* lg = (const float*)d_in[3];      // [B,S,V]
    float* out0 = (float*)d_out;                       // filtered, 512000 floats
    float* out1 = out0 + (size_t)BB * SS * KK;         // ids as float, 512000

    dim3 grid(BB * SS), block(NT);
    hipLaunchKernelGGL(langevin_topk_kernel, grid, block, 0, stream,
                       gx, cb, W, lg, out0, out1);
}

// Round 4
// 160.572 us; speedup vs baseline: 1.3452x; 1.0528x over previous
//
#include <hip/hip_runtime.h>
#include <stdint.h>

// Problem constants (from reference setup_inputs)
#define BB 4
#define SS 512
#define EE 64
#define VV 50257
#define KK 250        // K_VAL
// STEP_SIZE = 0.1 -> multiply by 10; TEMP = 1.0 -> no-op

#define CAP 4096
#define NT 512

// Float-domain pre-filter threshold for the fast path. fkey(2.0f)=0xC0000000.
// Correctness does NOT depend on it: if fewer than KK values exceed it (or
// more than CAP do), the kernel falls back to an exact full-histogram path.
#define THR0 2.0f
#define K0 0xC0000000u
#define BIN0 3072u    // K0 >> 20

typedef float float4n __attribute__((ext_vector_type(4)));  // native vec for nontemporal

__device__ __forceinline__ unsigned fkey(float f) {
    // monotonic map: larger float -> larger unsigned
    unsigned u = __float_as_uint(f);
    return (u & 0x80000000u) ? ~u : (u | 0x80000000u);
}

__global__ __launch_bounds__(NT, 8)
void langevin_topk_kernel(const float* __restrict__ gx,
                          const float* __restrict__ cb,
                          const float* __restrict__ W,
                          const float* __restrict__ logits,
                          float* __restrict__ out0,   // filtered [B*S, K]
                          float* __restrict__ out1)   // ids as float [B*S, K]
{
    __shared__ unsigned long long cand[CAP];   // 32 KB candidate buffer
    __shared__ unsigned long long buf2[512];   // 4 KB compact buffer; fast-path hist aliases
    __shared__ unsigned chunkSum[256];         // 1 KB
    __shared__ float gx_s[EE], cb_s[EE];
    __shared__ unsigned sThreshKey, sCnt, sCnt2;

    const int row  = blockIdx.x;               // b*S + s
    const int tid  = threadIdx.x;
    const float* rp = logits + (size_t)row * VV;

    unsigned* hist = (unsigned*)buf2;          // 1024 bins, fast path only

    for (int i = tid; i < 1024; i += NT) hist[i] = 0u;
    if (tid < EE) {
        gx_s[tid] = gx[(size_t)row * EE + tid];
        cb_s[tid] = cb[(size_t)row * EE + tid];
    }
    if (tid == 0) { sCnt = 0u; sCnt2 = 0u; }
    __syncthreads();

    // rare-path candidate emit: ~1100 per row total -> plain LDS atomic is fine
    auto emit = [&](float f, int idx) {
        if (f >= THR0) {
            unsigned p = atomicAdd(&sCnt, 1u);
            if (p < CAP)
                cand[p] = ((unsigned long long)fkey(f) << 32) | (unsigned)(~idx);
        }
    };

    // ---- alignment peel: row offset = row*50257, 50257 % 4 == 1 ----
    const int mis  = row & 3;
    const int peel = (4 - mis) & 3;
    const int nb   = (VV - peel) >> 2;
    const int tail0 = peel + nb * 4;
    const float4n* rp4 = (const float4n*)(rp + peel);

    // ---- single streaming pass: cheap float compare filter, 4 loads in flight ----
    if (tid < peel) emit(rp[tid], tid);
    int i = tid;
    for (; i + 3 * NT < nb; i += 4 * NT) {
        float4n a = __builtin_nontemporal_load(&rp4[i]);
        float4n b = __builtin_nontemporal_load(&rp4[i + NT]);
        float4n c = __builtin_nontemporal_load(&rp4[i + 2 * NT]);
        float4n d = __builtin_nontemporal_load(&rp4[i + 3 * NT]);
        int ia = peel + 4 * i, ib = peel + 4 * (i + NT), ic = peel + 4 * (i + 2 * NT), id_ = peel + 4 * (i + 3 * NT);
        emit(a.x, ia + 0); emit(a.y, ia + 1); emit(a.z, ia + 2); emit(a.w, ia + 3);
        emit(b.x, ib + 0); emit(b.y, ib + 1); emit(b.z, ib + 2); emit(b.w, ib + 3);
        emit(c.x, ic + 0); emit(c.y, ic + 1); emit(c.z, ic + 2); emit(c.w, ic + 3);
        emit(d.x, id_ + 0); emit(d.y, id_ + 1); emit(d.z, id_ + 2); emit(d.w, id_ + 3);
    }
    for (; i < nb; i += NT) {
        float4n a = __builtin_nontemporal_load(&rp4[i]);
        int ia = peel + 4 * i;
        emit(a.x, ia + 0); emit(a.y, ia + 1); emit(a.z, ia + 2); emit(a.w, ia + 3);
    }
    for (int t = tail0 + tid; t < VV; t += NT) emit(rp[t], t);
    __syncthreads();

    const unsigned n0 = sCnt;
    unsigned long long* srt;
    unsigned P;

    if (n0 >= KK && n0 <= CAP) {
        // ================= FAST PATH =================
        // histogram the collected candidates (all have key >= K0)
        for (unsigned j = tid; j < n0; j += NT)
            atomicAdd(&hist[((unsigned)(cand[j] >> 32) >> 20) - BIN0], 1u);
        __syncthreads();

        if (tid < 256) {
            chunkSum[tid] = hist[tid * 4] + hist[tid * 4 + 1] + hist[tid * 4 + 2] + hist[tid * 4 + 3];
        }
        __syncthreads();
        if (tid < 256) {
            unsigned g = 0;
            for (int u = tid + 1; u < 256; ++u) g += chunkSum[u];
            unsigned cs = chunkSum[tid];
            if (g < KK && g + cs >= KK) {
                unsigned cum = g;
                #pragma unroll
                for (int b = 3; b >= 0; --b) {
                    unsigned c = hist[tid * 4 + b];
                    if (cum + c >= KK) { sThreshKey = ((unsigned)(tid * 4 + b) + BIN0) << 20; break; }
                    cum += c;
                }
            }
        }
        __syncthreads();
        const unsigned keyT = sThreshKey;
        __syncthreads();   // hist (aliases buf2) dead; buf2 may now be written

        // compact survivors (>= keyT) into buf2
        for (unsigned j = tid; j < n0; j += NT) {
            unsigned long long c = cand[j];
            if ((unsigned)(c >> 32) >= keyT) {
                unsigned p = atomicAdd(&sCnt2, 1u);
                if (p < 512) buf2[p] = c;
            }
        }
        __syncthreads();
        unsigned nc = sCnt2;
        if (nc <= 512) {
            srt = buf2;
            P = 256; while (P < nc) P <<= 1;
            for (unsigned j = nc + tid; j < P; j += NT) buf2[j] = 0ull;
        } else {
            // threshold bin unusually fat: sort the whole candidate buffer
            srt = cand;
            P = 256; while (P < n0) P <<= 1;
            for (unsigned j = n0 + tid; j < P; j += NT) cand[j] = 0ull;
        }
        __syncthreads();
    } else {
        // ================= EXACT FALLBACK (never taken for N(0,1) data) =================
        unsigned* hist4 = (unsigned*)cand;     // 4096 bins alias candidate space
        for (int j = tid; j < 4096; j += NT) hist4[j] = 0u;
        if (tid == 0) sCnt = 0u;
        __syncthreads();
        if (tid < peel) atomicAdd(&hist4[fkey(rp[tid]) >> 20], 1u);
        for (int j = tid; j < nb; j += NT) {
            float4n v = rp4[j];
            atomicAdd(&hist4[fkey(v.x) >> 20], 1u);
            atomicAdd(&hist4[fkey(v.y) >> 20], 1u);
            atomicAdd(&hist4[fkey(v.z) >> 20], 1u);
            atomicAdd(&hist4[fkey(v.w) >> 20], 1u);
        }
        for (int t = tail0 + tid; t < VV; t += NT) atomicAdd(&hist4[fkey(rp[t]) >> 20], 1u);
        __syncthreads();
        if (tid < 256) {
            unsigned cs = 0;
            #pragma unroll
            for (int b = 0; b < 16; ++b) cs += hist4[tid * 16 + b];
            chunkSum[tid] = cs;
        }
        __syncthreads();
        if (tid < 256) {
            unsigned g = 0;
            for (int u = tid + 1; u < 256; ++u) g += chunkSum[u];
            unsigned cs = chunkSum[tid];
            if (g < KK && g + cs >= KK) {
                unsigned cum = g;
                #pragma unroll
                for (int b = 15; b >= 0; --b) {
                    unsigned c = hist4[tid * 16 + b];
                    if (cum + c >= KK) { sThreshKey = ((unsigned)(tid * 16 + b)) << 20; break; }
                    cum += c;
                }
            }
        }
        __syncthreads();
        const unsigned keyT = sThreshKey;
        __syncthreads();   // hist4 aliases cand -> must drain before collection writes

        auto emit2 = [&](unsigned k, int idx) {
            if (k >= keyT) {
                unsigned p = atomicAdd(&sCnt, 1u);
                if (p < CAP) cand[p] = ((unsigned long long)k << 32) | (unsigned)(~idx);
            }
        };
        if (tid < peel) emit2(fkey(rp[tid]), tid);
        for (int j = tid; j < nb; j += NT) {
            float4n v = rp4[j];
            int ia = peel + 4 * j;
            emit2(fkey(v.x), ia + 0); emit2(fkey(v.y), ia + 1);
            emit2(fkey(v.z), ia + 2); emit2(fkey(v.w), ia + 3);
        }
        for (int t = tail0 + tid; t < VV; t += NT) emit2(fkey(rp[t]), t);
        __syncthreads();
        unsigned n1 = sCnt; if (n1 > CAP) n1 = CAP;
        srt = cand;
        P = 256; while (P < n1) P <<= 1;
        for (unsigned j = n1 + tid; j < P; j += NT) cand[j] = 0ull;
        __syncthreads();
    }

    // ---- bitonic sort descending on composite (key<<32 | ~idx) ----
    for (unsigned k = 2; k <= P; k <<= 1) {
        for (unsigned j = k >> 1; j > 0; j >>= 1) {
            for (unsigned i2 = tid; i2 < P; i2 += NT) {
                unsigned l = i2 ^ j;
                if (l > i2) {
                    unsigned long long a = srt[i2], b = srt[l];
                    bool up = ((i2 & k) == 0);
                    if (up ? (a < b) : (a > b)) { srt[i2] = b; srt[l] = a; }
                }
            }
            __syncthreads();
        }
    }

    // ---- epilogue: proposal value at the K selected ids ----
    float gxcb = 0.f, cbn = 0.f;
    #pragma unroll
    for (int e = 0; e < EE; ++e) { gxcb += gx_s[e] * cb_s[e]; cbn += cb_s[e] * cb_s[e]; }

    if (tid < KK) {
        unsigned long long ck = srt[tid];
        unsigned v = ~((unsigned)ck);
        const float4* Wv = (const float4*)(W + (size_t)v * EE);
        float d1 = 0.f, d2 = 0.f, wn = 0.f;
        #pragma unroll
        for (int j2 = 0; j2 < 16; ++j2) {
            float4 w = Wv[j2];
            float a0 = gx_s[4*j2+0], a1 = gx_s[4*j2+1], a2 = gx_s[4*j2+2], a3 = gx_s[4*j2+3];
            float b0 = cb_s[4*j2+0], b1 = cb_s[4*j2+1], b2 = cb_s[4*j2+2], b3 = cb_s[4*j2+3];
            d1 += a0*w.x + a1*w.y + a2*w.z + a3*w.w;
            d2 += b0*w.x + b1*w.y + b2*w.z + b3*w.w;
            wn += w.x*w.x + w.y*w.y + w.z*w.z + w.w*w.w;
        }
        // dist = 0.5*(t1_1 - t1_2) + (t2_1 - 2*t2_2 + t2_3)/0.1 ; out = -dist / TEMP
        float unf = -(0.5f * (d1 - gxcb) + (wn - 2.0f * d2 + cbn) * 10.0f);
        out0[(size_t)row * KK + tid] = unf;
        out1[(size_t)row * KK + tid] = (float)v;
    }
}

extern "C" void kernel_launch(void* const* d_in, const int* in_sizes, int n_in,
                              void* d_out, int out_size, void* d_ws, size_t ws_size,
                              hipStream_t stream) {
    const float* gx = (const float*)d_in[0];      // [B,S,E]
    const float* cb = (const float*)d_in[1];      // [B,S,E]
    const float* W  = (const float*)d_in[2];      // [V,E]
    const float* lg = (const float*)d_in[3];      // [B,S,V]
    float* out0 = (float*)d_out;                       // filtered, 512000 floats
    float* out1 = out0 + (size_t)BB * SS * KK;         // ids as float, 512000

    dim3 grid(BB * SS), block(NT);
    hipLaunchKernelGGL(langevin_topk_kernel, grid, block, 0, stream,
                       gx, cb, W, lg, out0, out1);
}